// Round 9
// baseline (216.997 us; speedup 1.0000x reference)
//
#include <hip/hip_runtime.h>
#include <hip/hip_bf16.h>
#include <cmath>

typedef _Float16 half_t;
typedef half_t half4 __attribute__((ext_vector_type(4)));
typedef half_t half8 __attribute__((ext_vector_type(8)));
typedef float f32x4 __attribute__((ext_vector_type(4)));

#define N_HEADS 16
#define HD      64
#define T_SEQ   2048
#define B_SZ    2
#define C_DIM   1024
#define M_ROWS  (B_SZ * T_SEQ)   /* 4096 */
#define N_QKV   (3 * C_DIM)      /* 3072 */
#define QSCALE  0.18033688f      /* 0.125 * log2(e), folded into Q at rope */

__device__ inline void load_lds16(const half_t* g, half_t* l) {
  __builtin_amdgcn_global_load_lds(
      (const __attribute__((address_space(1))) void*)g,
      (__attribute__((address_space(3))) void*)l, 16, 0, 0);
}

// ---- fused prep: x->f16 cvt (blocks 0..4095), w_attn^T (..4863), w_proj^T ----
__global__ __launch_bounds__(256) void k_prep(const float* __restrict__ x,
                                              half_t* __restrict__ xb,
                                              const float* __restrict__ wa,
                                              half_t* __restrict__ wT,
                                              const float* __restrict__ wp,
                                              half_t* __restrict__ wpT) {
  __shared__ float tile[64][65];
  int bid = blockIdx.x, tid = threadIdx.x;
  if (bid < 4096) {
    int i = (bid * 256 + tid) * 4;
    float4 v = *(const float4*)(x + i);
    half_t o[4] = {(half_t)v.x, (half_t)v.y, (half_t)v.z, (half_t)v.w};
    *(ulong1*)(xb + i) = *(ulong1*)o;
    return;
  }
  const float* in; half_t* out; int K, N, id;
  if (bid < 4096 + 768) { id = bid - 4096; in = wa; out = wT;  K = 1024; N = 3072; }
  else                  { id = bid - 4864; in = wp; out = wpT; K = 1024; N = 1024; }
  int n0 = (id % (N / 64)) * 64, k0 = (id / (N / 64)) * 64;
  int tx = tid & 63, ty = tid >> 6;
  #pragma unroll
  for (int i = 0; i < 64; i += 4)
    tile[ty + i][tx] = in[(size_t)(k0 + ty + i) * N + n0 + tx];
  __syncthreads();
  #pragma unroll
  for (int i = 0; i < 64; i += 4) {
    int r = ty + i;
    out[(size_t)(n0 + r) * K + k0 + tx] = (half_t)tile[tx][r];
  }
}

// ------------- GEMM: C = A(f16,[M][K]) * Bt(f16,[N][K])^T + bias, OT out ----
// 128xTN tile, BK=64, global_load_lds width-16 into XOR-swizzled LDS.
template <typename OT, int TN>
__global__ __launch_bounds__(256) void k_gemm(const half_t* __restrict__ A,
                                              const half_t* __restrict__ Bt,
                                              const float* __restrict__ bias,
                                              OT* __restrict__ C,
                                              int M, int N, int K) {
  constexpr int NI = TN / 32;          // n-fragments per wave
  __shared__ half_t As[128 * 64];
  __shared__ half_t Bs[TN * 64];
  int tid = threadIdx.x;
  int wave = tid >> 6, lane = tid & 63;
  int lane15 = lane & 15, quad = lane >> 4;
  int wm = (wave >> 1) * 64, wn = (wave & 1) * (TN / 2);
  int bm0 = blockIdx.y * 128, bn0 = blockIdx.x * TN;
  f32x4 acc[4][NI] = {};

  for (int kb = 0; kb < K; kb += 64) {
    const half_t* Ag = A + (size_t)bm0 * K + kb;
    const half_t* Bg = Bt + (size_t)bn0 * K + kb;
    __syncthreads();
    #pragma unroll
    for (int p = 0; p < 4; p++) {
      int fc = wave * 4 * 64 + p * 64 + lane;
      int r = fc >> 3, c = (fc & 7) ^ (r & 7);
      load_lds16(Ag + (size_t)r * K + c * 8, As + (wave * 4 + p) * 512);
    }
    #pragma unroll
    for (int p = 0; p < NI; p++) {
      int fc = wave * NI * 64 + p * 64 + lane;
      int r = fc >> 3, c = (fc & 7) ^ (r & 7);
      load_lds16(Bg + (size_t)r * K + c * 8, Bs + (wave * NI + p) * 512);
    }
    __syncthreads();
    #pragma unroll
    for (int ks = 0; ks < 2; ks++) {
      half8 af[4], bf[NI];
      #pragma unroll
      for (int i = 0; i < 4; i++) {
        int Ra = wm + i * 16 + lane15;
        af[i] = *(const half8*)(As + Ra * 64 + ((ks * 4 + quad) ^ (Ra & 7)) * 8);
      }
      #pragma unroll
      for (int i = 0; i < NI; i++) {
        int Rb = wn + i * 16 + lane15;
        bf[i] = *(const half8*)(Bs + Rb * 64 + ((ks * 4 + quad) ^ (Rb & 7)) * 8);
      }
      #pragma unroll
      for (int mi = 0; mi < 4; mi++)
        #pragma unroll
        for (int ni = 0; ni < NI; ni++)
          acc[mi][ni] = __builtin_amdgcn_mfma_f32_16x16x32_f16(af[mi], bf[ni], acc[mi][ni], 0, 0, 0);
    }
  }
  #pragma unroll
  for (int mi = 0; mi < 4; mi++)
    #pragma unroll
    for (int ni = 0; ni < NI; ni++) {
      int n = bn0 + wn + ni * 16 + lane15;
      float bv = bias[n];
      int mrow = bm0 + wm + mi * 16 + quad * 4;
      #pragma unroll
      for (int r = 0; r < 4; r++)
        C[(size_t)(mrow + r) * N + n] = (OT)(acc[mi][ni][r] + bv);
    }
}

// ------------- RoPE + reorg (qkv f16); Q pre-scaled by 0.125*log2(e) -------------
__global__ __launch_bounds__(256) void k_rope(const half_t* __restrict__ qkv,
                                              half_t* __restrict__ Q,
                                              half_t* __restrict__ Ko,
                                              half_t* __restrict__ Vt) {
  __shared__ float vt[64][65];
  int bh = blockIdx.y;
  int b = bh >> 4, h = bh & 15;
  int t0 = blockIdx.x * 64;
  int tid = threadIdx.x;
  int trow = tid >> 5, i = tid & 31;           // 8 t-rows x 32 freq
  float inv = exp2f(-(float)i * (13.287712379549449f / 32.0f));
  #pragma unroll
  for (int p = 0; p < 8; p++) {
    int tloc = p * 8 + trow;
    int t = t0 + tloc;
    const half_t* row = qkv + (size_t)(b * T_SEQ + t) * N_QKV;
    float q1 = (float)row[h * 64 + i],        q2 = (float)row[h * 64 + i + 32];
    float k1 = (float)row[1024 + h * 64 + i], k2 = (float)row[1024 + h * 64 + i + 32];
    float v1 = (float)row[2048 + h * 64 + i], v2 = (float)row[2048 + h * 64 + i + 32];
    float s, c;
    sincosf((float)t * inv, &s, &c);
    size_t base = ((size_t)bh * T_SEQ + t) * HD;
    Q[base + i]       = (half_t)((q1 * c - q2 * s) * QSCALE);
    Q[base + i + 32]  = (half_t)((q1 * s + q2 * c) * QSCALE);
    Ko[base + i]      = (half_t)(k1 * c - k2 * s);
    Ko[base + i + 32] = (half_t)(k1 * s + k2 * c);
    vt[i][tloc]      = v1;
    vt[i + 32][tloc] = v2;
  }
  __syncthreads();
  int d = tid >> 6, tc = tid & 63;             // 4 d-rows x 64 t
  #pragma unroll
  for (int p = 0; p < 16; p++) {
    int dd = p * 4 + d;
    Vt[((size_t)bh * HD + dd) * T_SEQ + t0 + tc] = (half_t)vt[dd][tc];
  }
}

// ------------- causal flash: R4 body + 1024-block occupancy fix -------------
// grid (32, B*H): ONE 64-q tile per block (4 waves, each wave owns 16 q and
// computes the full 64-kv tile -> O,l finished in-wave, y written directly;
// VGPR ~56). K/V double-buffered in XOR-swizzled LDS via global_load_lds.
// Occupancy: 1024 blocks = 4 blocks/CU = 4 waves/SIMD (vs 2 with pairing).
// Balance: under linear mod-256 dispatch, CU c gets blocks x in the group
// {g, g+8, g+16, g+24}; qt map {2g, 2g+1, 31-2g, 30-2g} makes every group's
// trip-count sum exactly 66. Diagonal tile peeled (hot loop mask-free).
__global__ __launch_bounds__(256) void k_flash(const half_t* __restrict__ Qg,
                                               const half_t* __restrict__ Kg,
                                               const half_t* __restrict__ Vg,
                                               half_t* __restrict__ y) {
  __shared__ half_t Ks[2][4096];
  __shared__ half_t Vs[2][4096];
  int bh = blockIdx.y;
  int b = bh >> 4, h = bh & 15;
  int x = blockIdx.x, g = x & 7, m = x >> 3;
  int qt = (m == 0) ? 2 * g : (m == 1) ? 2 * g + 1
         : (m == 2) ? 31 - 2 * g : 30 - 2 * g;
  int tid = threadIdx.x;
  int wave = tid >> 6, lane = tid & 63;
  int lane15 = lane & 15, quad = lane >> 4;
  const half_t* Qb = Qg + (size_t)bh * T_SEQ * HD;
  const half_t* Kb = Kg + (size_t)bh * T_SEQ * HD;
  const half_t* Vb = Vg + (size_t)bh * HD * T_SEQ;

  #define STAGE(buf, kv0)                                                      \
    {                                                                          \
      _Pragma("unroll")                                                        \
      for (int pp = 0; pp < 2; pp++) {                                         \
        int fc = (wave * 2 + pp) * 64 + lane;                                  \
        int rr = fc >> 3, cc = (fc & 7) ^ (rr & 7);                            \
        load_lds16(Kb + (size_t)((kv0) + rr) * HD + cc * 8,                    \
                   &Ks[buf][0] + fc * 8);                                      \
        load_lds16(Vb + (size_t)rr * T_SEQ + (kv0) + cc * 8,                   \
                   &Vs[buf][0] + fc * 8);                                      \
      }                                                                        \
    }

  int q0 = qt * 64;
  int qrow = q0 + wave * 16 + lane15;      // this wave's q column (S^T B-op n)
  half8 bq0 = *(const half8*)(Qb + (size_t)qrow * HD + quad * 8);
  half8 bq1 = *(const half8*)(Qb + (size_t)qrow * HD + 32 + quad * 8);
  f32x4 ot[4] = {};                        // O^T: d = nm*16+quad*4+r, q = lane15
  float l = 0.f;

  STAGE(0, 0);
  // ---- hot loop: off-diagonal tiles, no mask code ----
  for (int j = 0; j < qt; j++) {
    int buf = j & 1;
    __syncthreads();                       // stage(j) DMA drained & visible
    STAGE(buf ^ 1, (j + 1) * 64);          // prefetch overlaps compute
    const half_t* Kt = &Ks[buf][0];
    const half_t* Vt = &Vs[buf][0];
    f32x4 sacc[4];
    #pragma unroll
    for (int s = 0; s < 4; s++) {
      int R = s * 16 + lane15;
      half8 ak0 = *(const half8*)(Kt + R * 64 + ((quad) ^ (R & 7)) * 8);
      half8 ak1 = *(const half8*)(Kt + R * 64 + ((4 + quad) ^ (R & 7)) * 8);
      f32x4 z = {};
      z = __builtin_amdgcn_mfma_f32_16x16x32_f16(ak0, bq0, z, 0, 0, 0);
      sacc[s] = __builtin_amdgcn_mfma_f32_16x16x32_f16(ak1, bq1, z, 0, 0, 0);
    }
    #pragma unroll
    for (int s = 0; s < 4; s++) {
      half4 bp;
      #pragma unroll
      for (int r = 0; r < 4; r++) {
        float p = exp2f(fminf(sacc[s][r], 14.0f));
        l += p;
        bp[r] = (half_t)p;
      }
      #pragma unroll
      for (int nm = 0; nm < 4; nm++) {
        int Rv = nm * 16 + lane15;
        half4 av = *(const half4*)(Vt + Rv * 64 +
                                   ((2 * s + (quad >> 1)) ^ (Rv & 7)) * 8 +
                                   (quad & 1) * 4);
        ot[nm] = __builtin_amdgcn_mfma_f32_16x16x16f16(av, bp, ot[nm], 0, 0, 0);
      }
    }
  }
  // ---- peeled diagonal tile (mask kv > q; same tile base as q0) ----
  {
    int buf = qt & 1;
    __syncthreads();
    const half_t* Kt = &Ks[buf][0];
    const half_t* Vt = &Vs[buf][0];
    f32x4 sacc[4];
    #pragma unroll
    for (int s = 0; s < 4; s++) {
      int R = s * 16 + lane15;
      half8 ak0 = *(const half8*)(Kt + R * 64 + ((quad) ^ (R & 7)) * 8);
      half8 ak1 = *(const half8*)(Kt + R * 64 + ((4 + quad) ^ (R & 7)) * 8);
      f32x4 z = {};
      z = __builtin_amdgcn_mfma_f32_16x16x32_f16(ak0, bq0, z, 0, 0, 0);
      sacc[s] = __builtin_amdgcn_mfma_f32_16x16x32_f16(ak1, bq1, z, 0, 0, 0);
    }
    #pragma unroll
    for (int s = 0; s < 4; s++) {
      half4 bp;
      #pragma unroll
      for (int r = 0; r < 4; r++) {
        float sv = sacc[s][r];
        if (s * 16 + quad * 4 + r > wave * 16 + lane15) sv = -1.0e30f;
        float p = exp2f(fminf(sv, 14.0f));
        l += p;
        bp[r] = (half_t)p;
      }
      #pragma unroll
      for (int nm = 0; nm < 4; nm++) {
        int Rv = nm * 16 + lane15;
        half4 av = *(const half4*)(Vt + Rv * 64 +
                                   ((2 * s + (quad >> 1)) ^ (Rv & 7)) * 8 +
                                   (quad & 1) * 4);
        ot[nm] = __builtin_amdgcn_mfma_f32_16x16x16f16(av, bp, ot[nm], 0, 0, 0);
      }
    }
  }

  // l: sum across the 4 quads holding this q-column, then write y
  l += __shfl_xor(l, 16);
  l += __shfl_xor(l, 32);
  float invl = 1.0f / l;
  int t = q0 + wave * 16 + lane15;
  half_t* yr = y + (size_t)(b * T_SEQ + t) * C_DIM + h * 64;
  #pragma unroll
  for (int nm = 0; nm < 4; nm++) {
    half4 o4;
    #pragma unroll
    for (int r = 0; r < 4; r++) o4[r] = (half_t)(ot[nm][r] * invl);
    *(half4*)(yr + nm * 16 + quad * 4) = o4;   // 8B store
  }
  #undef STAGE
}

extern "C" void kernel_launch(void* const* d_in, const int* in_sizes, int n_in,
                              void* d_out, int out_size, void* d_ws, size_t ws_size,
                              hipStream_t stream) {
  const float* x      = (const float*)d_in[0];
  const float* w_attn = (const float*)d_in[1];
  const float* b_attn = (const float*)d_in[2];
  const float* w_proj = (const float*)d_in[3];
  const float* b_proj = (const float*)d_in[4];
  float* out = (float*)d_out;

  char* ws = (char*)d_ws;
  const size_t MB = 1u << 20;
  half_t* xb  = (half_t*)(ws);             // 8 MB  x in f16
  half_t* wT  = (half_t*)(ws + 8 * MB);    // 6 MB  w_attn^T f16 [3072][1024]
  half_t* wpT = (half_t*)(ws + 14 * MB);   // 2 MB  w_proj^T f16 [1024][1024]
  half_t* Q   = (half_t*)(ws + 16 * MB);   // 8 MB  [bh][t][d]  (pre-scaled)
  half_t* Kb  = (half_t*)(ws + 24 * MB);   // 8 MB  [bh][t][d]
  half_t* Vt  = (half_t*)(ws + 32 * MB);   // 8 MB  [bh][d][t]
  half_t* qkv = (half_t*)(ws + 40 * MB);   // 24 MB f16 qkv
  half_t* y   = (half_t*)(ws + 40 * MB);   // aliases qkv (dead after k_rope)

  k_prep<<<4096 + 768 + 256, 256, 0, stream>>>(x, xb, w_attn, wT, w_proj, wpT);
  k_gemm<half_t, 128><<<dim3(N_QKV / 128, M_ROWS / 128), 256, 0, stream>>>(
      xb, wT, b_attn, qkv, M_ROWS, N_QKV, C_DIM);
  k_rope<<<dim3(T_SEQ / 64, B_SZ * N_HEADS), 256, 0, stream>>>(qkv, Q, Kb, Vt);
  k_flash<<<dim3(32, B_SZ * N_HEADS), 256, 0, stream>>>(Q, Kb, Vt, y);
  k_gemm<float, 64><<<dim3(C_DIM / 64, M_ROWS / 128), 256, 0, stream>>>(
      y, wpT, b_proj, out, M_ROWS, C_DIM, C_DIM);
}

// Round 10
// 198.903 us; speedup vs baseline: 1.0910x; 1.0910x over previous
//
#include <hip/hip_runtime.h>
#include <hip/hip_bf16.h>
#include <cmath>

typedef _Float16 half_t;
typedef half_t half4 __attribute__((ext_vector_type(4)));
typedef half_t half8 __attribute__((ext_vector_type(8)));
typedef float f32x4 __attribute__((ext_vector_type(4)));

#define N_HEADS 16
#define HD      64
#define T_SEQ   2048
#define B_SZ    2
#define C_DIM   1024
#define M_ROWS  (B_SZ * T_SEQ)   /* 4096 */
#define N_QKV   (3 * C_DIM)      /* 3072 */
#define QSCALE  0.18033688f      /* 0.125 * log2(e), folded into Q at rope */

__device__ inline void load_lds16(const half_t* g, half_t* l) {
  __builtin_amdgcn_global_load_lds(
      (const __attribute__((address_space(1))) void*)g,
      (__attribute__((address_space(3))) void*)l, 16, 0, 0);
}

// ---- fused prep: x->f16 cvt (blocks 0..4095), w_attn^T (..4863), w_proj^T ----
__global__ __launch_bounds__(256) void k_prep(const float* __restrict__ x,
                                              half_t* __restrict__ xb,
                                              const float* __restrict__ wa,
                                              half_t* __restrict__ wT,
                                              const float* __restrict__ wp,
                                              half_t* __restrict__ wpT) {
  __shared__ float tile[64][65];
  int bid = blockIdx.x, tid = threadIdx.x;
  if (bid < 4096) {
    int i = (bid * 256 + tid) * 4;
    float4 v = *(const float4*)(x + i);
    half_t o[4] = {(half_t)v.x, (half_t)v.y, (half_t)v.z, (half_t)v.w};
    *(ulong1*)(xb + i) = *(ulong1*)o;
    return;
  }
  const float* in; half_t* out; int K, N, id;
  if (bid < 4096 + 768) { id = bid - 4096; in = wa; out = wT;  K = 1024; N = 3072; }
  else                  { id = bid - 4864; in = wp; out = wpT; K = 1024; N = 1024; }
  int n0 = (id % (N / 64)) * 64, k0 = (id / (N / 64)) * 64;
  int tx = tid & 63, ty = tid >> 6;
  #pragma unroll
  for (int i = 0; i < 64; i += 4)
    tile[ty + i][tx] = in[(size_t)(k0 + ty + i) * N + n0 + tx];
  __syncthreads();
  #pragma unroll
  for (int i = 0; i < 64; i += 4) {
    int r = ty + i;
    out[(size_t)(n0 + r) * K + k0 + tx] = (half_t)tile[tx][r];
  }
}

// ------------- GEMM: C = A(f16,[M][K]) * Bt(f16,[N][K])^T + bias, OT out ----
// 128xTN tile, BK=64, global_load_lds width-16 into XOR-swizzled LDS.
template <typename OT, int TN>
__global__ __launch_bounds__(256) void k_gemm(const half_t* __restrict__ A,
                                              const half_t* __restrict__ Bt,
                                              const float* __restrict__ bias,
                                              OT* __restrict__ C,
                                              int M, int N, int K) {
  constexpr int NI = TN / 32;          // n-fragments per wave
  __shared__ half_t As[128 * 64];
  __shared__ half_t Bs[TN * 64];
  int tid = threadIdx.x;
  int wave = tid >> 6, lane = tid & 63;
  int lane15 = lane & 15, quad = lane >> 4;
  int wm = (wave >> 1) * 64, wn = (wave & 1) * (TN / 2);
  int bm0 = blockIdx.y * 128, bn0 = blockIdx.x * TN;
  f32x4 acc[4][NI] = {};

  for (int kb = 0; kb < K; kb += 64) {
    const half_t* Ag = A + (size_t)bm0 * K + kb;
    const half_t* Bg = Bt + (size_t)bn0 * K + kb;
    __syncthreads();
    #pragma unroll
    for (int p = 0; p < 4; p++) {
      int fc = wave * 4 * 64 + p * 64 + lane;
      int r = fc >> 3, c = (fc & 7) ^ (r & 7);
      load_lds16(Ag + (size_t)r * K + c * 8, As + (wave * 4 + p) * 512);
    }
    #pragma unroll
    for (int p = 0; p < NI; p++) {
      int fc = wave * NI * 64 + p * 64 + lane;
      int r = fc >> 3, c = (fc & 7) ^ (r & 7);
      load_lds16(Bg + (size_t)r * K + c * 8, Bs + (wave * NI + p) * 512);
    }
    __syncthreads();
    #pragma unroll
    for (int ks = 0; ks < 2; ks++) {
      half8 af[4], bf[NI];
      #pragma unroll
      for (int i = 0; i < 4; i++) {
        int Ra = wm + i * 16 + lane15;
        af[i] = *(const half8*)(As + Ra * 64 + ((ks * 4 + quad) ^ (Ra & 7)) * 8);
      }
      #pragma unroll
      for (int i = 0; i < NI; i++) {
        int Rb = wn + i * 16 + lane15;
        bf[i] = *(const half8*)(Bs + Rb * 64 + ((ks * 4 + quad) ^ (Rb & 7)) * 8);
      }
      #pragma unroll
      for (int mi = 0; mi < 4; mi++)
        #pragma unroll
        for (int ni = 0; ni < NI; ni++)
          acc[mi][ni] = __builtin_amdgcn_mfma_f32_16x16x32_f16(af[mi], bf[ni], acc[mi][ni], 0, 0, 0);
    }
  }
  #pragma unroll
  for (int mi = 0; mi < 4; mi++)
    #pragma unroll
    for (int ni = 0; ni < NI; ni++) {
      int n = bn0 + wn + ni * 16 + lane15;
      float bv = bias[n];
      int mrow = bm0 + wm + mi * 16 + quad * 4;
      #pragma unroll
      for (int r = 0; r < 4; r++)
        C[(size_t)(mrow + r) * N + n] = (OT)(acc[mi][ni][r] + bv);
    }
}

// ------------- RoPE + reorg (qkv f16); Q pre-scaled by 0.125*log2(e) -------------
__global__ __launch_bounds__(256) void k_rope(const half_t* __restrict__ qkv,
                                              half_t* __restrict__ Q,
                                              half_t* __restrict__ Ko,
                                              half_t* __restrict__ Vt) {
  __shared__ float vt[64][65];
  int bh = blockIdx.y;
  int b = bh >> 4, h = bh & 15;
  int t0 = blockIdx.x * 64;
  int tid = threadIdx.x;
  int trow = tid >> 5, i = tid & 31;           // 8 t-rows x 32 freq
  float inv = exp2f(-(float)i * (13.287712379549449f / 32.0f));
  #pragma unroll
  for (int p = 0; p < 8; p++) {
    int tloc = p * 8 + trow;
    int t = t0 + tloc;
    const half_t* row = qkv + (size_t)(b * T_SEQ + t) * N_QKV;
    float q1 = (float)row[h * 64 + i],        q2 = (float)row[h * 64 + i + 32];
    float k1 = (float)row[1024 + h * 64 + i], k2 = (float)row[1024 + h * 64 + i + 32];
    float v1 = (float)row[2048 + h * 64 + i], v2 = (float)row[2048 + h * 64 + i + 32];
    float s, c;
    sincosf((float)t * inv, &s, &c);
    size_t base = ((size_t)bh * T_SEQ + t) * HD;
    Q[base + i]       = (half_t)((q1 * c - q2 * s) * QSCALE);
    Q[base + i + 32]  = (half_t)((q1 * s + q2 * c) * QSCALE);
    Ko[base + i]      = (half_t)(k1 * c - k2 * s);
    Ko[base + i + 32] = (half_t)(k1 * s + k2 * c);
    vt[i][tloc]      = v1;
    vt[i + 32][tloc] = v2;
  }
  __syncthreads();
  int d = tid >> 6, tc = tid & 63;             // 4 d-rows x 64 t
  #pragma unroll
  for (int p = 0; p < 16; p++) {
    int dd = p * 4 + d;
    Vt[((size_t)bh * HD + dd) * T_SEQ + t0 + tc] = (half_t)vt[dd][tc];
  }
}

// ------------- causal flash: R4 body, CU-correct balance map -------------
// grid (32, B*H): ONE 64-q tile per block; 1024 blocks = 4/CU = 4 waves/SIMD.
// Dispatch fact (measured R9): linear ID = x + 32*y, CU = linear % 256, so the
// 4 co-resident blocks of a CU share x and have m = y>>3 = 0..3. qt = x ^ C[m]
// with C={0,31,1,30}: per-bh x->qt is a bijection (XOR), and per-CU trip sum =
// (x+1)+(31-x+1)+((x^1)+1)+(31-(x^1)+1) = 66 for EVERY x -> perfect balance
// with 4-way TLP. K/V double-buffered in XOR-swizzled LDS via global_load_lds;
// diagonal tile peeled (hot loop mask-free); max-free softmax.
__global__ __launch_bounds__(256) void k_flash(const half_t* __restrict__ Qg,
                                               const half_t* __restrict__ Kg,
                                               const half_t* __restrict__ Vg,
                                               half_t* __restrict__ y) {
  __shared__ half_t Ks[2][4096];
  __shared__ half_t Vs[2][4096];
  int bh = blockIdx.y;
  int b = bh >> 4, h = bh & 15;
  const int Cm[4] = {0, 31, 1, 30};
  int qt = (int)blockIdx.x ^ Cm[(blockIdx.y >> 3) & 3];
  int tid = threadIdx.x;
  int wave = tid >> 6, lane = tid & 63;
  int lane15 = lane & 15, quad = lane >> 4;
  const half_t* Qb = Qg + (size_t)bh * T_SEQ * HD;
  const half_t* Kb = Kg + (size_t)bh * T_SEQ * HD;
  const half_t* Vb = Vg + (size_t)bh * HD * T_SEQ;

  #define STAGE(buf, kv0)                                                      \
    {                                                                          \
      _Pragma("unroll")                                                        \
      for (int pp = 0; pp < 2; pp++) {                                         \
        int fc = (wave * 2 + pp) * 64 + lane;                                  \
        int rr = fc >> 3, cc = (fc & 7) ^ (rr & 7);                            \
        load_lds16(Kb + (size_t)((kv0) + rr) * HD + cc * 8,                    \
                   &Ks[buf][0] + fc * 8);                                      \
        load_lds16(Vb + (size_t)rr * T_SEQ + (kv0) + cc * 8,                   \
                   &Vs[buf][0] + fc * 8);                                      \
      }                                                                        \
    }

  int q0 = qt * 64;
  int qrow = q0 + wave * 16 + lane15;      // this wave's q column (S^T B-op n)
  half8 bq0 = *(const half8*)(Qb + (size_t)qrow * HD + quad * 8);
  half8 bq1 = *(const half8*)(Qb + (size_t)qrow * HD + 32 + quad * 8);
  f32x4 ot[4] = {};                        // O^T: d = nm*16+quad*4+r, q = lane15
  float l = 0.f;

  STAGE(0, 0);
  // ---- hot loop: off-diagonal tiles, no mask code ----
  for (int j = 0; j < qt; j++) {
    int buf = j & 1;
    __syncthreads();                       // stage(j) DMA drained & visible
    STAGE(buf ^ 1, (j + 1) * 64);          // prefetch overlaps compute
    const half_t* Kt = &Ks[buf][0];
    const half_t* Vt = &Vs[buf][0];
    f32x4 sacc[4];
    #pragma unroll
    for (int s = 0; s < 4; s++) {
      int R = s * 16 + lane15;
      half8 ak0 = *(const half8*)(Kt + R * 64 + ((quad) ^ (R & 7)) * 8);
      half8 ak1 = *(const half8*)(Kt + R * 64 + ((4 + quad) ^ (R & 7)) * 8);
      f32x4 z = {};
      z = __builtin_amdgcn_mfma_f32_16x16x32_f16(ak0, bq0, z, 0, 0, 0);
      sacc[s] = __builtin_amdgcn_mfma_f32_16x16x32_f16(ak1, bq1, z, 0, 0, 0);
    }
    #pragma unroll
    for (int s = 0; s < 4; s++) {
      half4 bp;
      #pragma unroll
      for (int r = 0; r < 4; r++) {
        float p = exp2f(fminf(sacc[s][r], 14.0f));
        l += p;
        bp[r] = (half_t)p;
      }
      #pragma unroll
      for (int nm = 0; nm < 4; nm++) {
        int Rv = nm * 16 + lane15;
        half4 av = *(const half4*)(Vt + Rv * 64 +
                                   ((2 * s + (quad >> 1)) ^ (Rv & 7)) * 8 +
                                   (quad & 1) * 4);
        ot[nm] = __builtin_amdgcn_mfma_f32_16x16x16f16(av, bp, ot[nm], 0, 0, 0);
      }
    }
  }
  // ---- peeled diagonal tile (mask kv > q) ----
  {
    int buf = qt & 1;
    __syncthreads();
    const half_t* Kt = &Ks[buf][0];
    const half_t* Vt = &Vs[buf][0];
    f32x4 sacc[4];
    #pragma unroll
    for (int s = 0; s < 4; s++) {
      int R = s * 16 + lane15;
      half8 ak0 = *(const half8*)(Kt + R * 64 + ((quad) ^ (R & 7)) * 8);
      half8 ak1 = *(const half8*)(Kt + R * 64 + ((4 + quad) ^ (R & 7)) * 8);
      f32x4 z = {};
      z = __builtin_amdgcn_mfma_f32_16x16x32_f16(ak0, bq0, z, 0, 0, 0);
      sacc[s] = __builtin_amdgcn_mfma_f32_16x16x32_f16(ak1, bq1, z, 0, 0, 0);
    }
    #pragma unroll
    for (int s = 0; s < 4; s++) {
      half4 bp;
      #pragma unroll
      for (int r = 0; r < 4; r++) {
        float sv = sacc[s][r];
        if (s * 16 + quad * 4 + r > wave * 16 + lane15) sv = -1.0e30f;
        float p = exp2f(fminf(sv, 14.0f));
        l += p;
        bp[r] = (half_t)p;
      }
      #pragma unroll
      for (int nm = 0; nm < 4; nm++) {
        int Rv = nm * 16 + lane15;
        half4 av = *(const half4*)(Vt + Rv * 64 +
                                   ((2 * s + (quad >> 1)) ^ (Rv & 7)) * 8 +
                                   (quad & 1) * 4);
        ot[nm] = __builtin_amdgcn_mfma_f32_16x16x16f16(av, bp, ot[nm], 0, 0, 0);
      }
    }
  }

  // l: sum across the 4 quads holding this q-column, then write y
  l += __shfl_xor(l, 16);
  l += __shfl_xor(l, 32);
  float invl = 1.0f / l;
  int t = q0 + wave * 16 + lane15;
  half_t* yr = y + (size_t)(b * T_SEQ + t) * C_DIM + h * 64;
  #pragma unroll
  for (int nm = 0; nm < 4; nm++) {
    half4 o4;
    #pragma unroll
    for (int r = 0; r < 4; r++) o4[r] = (half_t)(ot[nm][r] * invl);
    *(half4*)(yr + nm * 16 + quad * 4) = o4;   // 8B store
  }
  #undef STAGE
}

extern "C" void kernel_launch(void* const* d_in, const int* in_sizes, int n_in,
                              void* d_out, int out_size, void* d_ws, size_t ws_size,
                              hipStream_t stream) {
  const float* x      = (const float*)d_in[0];
  const float* w_attn = (const float*)d_in[1];
  const float* b_attn = (const float*)d_in[2];
  const float* w_proj = (const float*)d_in[3];
  const float* b_proj = (const float*)d_in[4];
  float* out = (float*)d_out;

  char* ws = (char*)d_ws;
  const size_t MB = 1u << 20;
  half_t* xb  = (half_t*)(ws);             // 8 MB  x in f16
  half_t* wT  = (half_t*)(ws + 8 * MB);    // 6 MB  w_attn^T f16 [3072][1024]
  half_t* wpT = (half_t*)(ws + 14 * MB);   // 2 MB  w_proj^T f16 [1024][1024]
  half_t* Q   = (half_t*)(ws + 16 * MB);   // 8 MB  [bh][t][d]  (pre-scaled)
  half_t* Kb  = (half_t*)(ws + 24 * MB);   // 8 MB  [bh][t][d]
  half_t* Vt  = (half_t*)(ws + 32 * MB);   // 8 MB  [bh][d][t]
  half_t* qkv = (half_t*)(ws + 40 * MB);   // 24 MB f16 qkv
  half_t* y   = (half_t*)(ws + 40 * MB);   // aliases qkv (dead after k_rope)

  k_prep<<<4096 + 768 + 256, 256, 0, stream>>>(x, xb, w_attn, wT, w_proj, wpT);
  k_gemm<half_t, 128><<<dim3(N_QKV / 128, M_ROWS / 128), 256, 0, stream>>>(
      xb, wT, b_attn, qkv, M_ROWS, N_QKV, C_DIM);
  k_rope<<<dim3(T_SEQ / 64, B_SZ * N_HEADS), 256, 0, stream>>>(qkv, Q, Kb, Vt);
  k_flash<<<dim3(32, B_SZ * N_HEADS), 256, 0, stream>>>(Q, Kb, Vt, y);
  k_gemm<float, 64><<<dim3(C_DIM / 64, M_ROWS / 128), 256, 0, stream>>>(
      y, wpT, b_proj, out, M_ROWS, C_DIM, C_DIM);
}